// Round 5
// baseline (133.301 us; speedup 1.0000x reference)
//
#include <hip/hip_runtime.h>
#include <stdint.h>

#define OBS 15
#define NTOT 50000
#define HDIM 64
#define NPB 32               // neighbors per block: 2 groups of 16 per wave-set
#define NBLK_N 1563          // ceil(50000/32); last block padded, blockIdx 0 = target
#define ZOFF (OBS * NPB * 8) // ushort index of the 16B zero slot in xbf

typedef __attribute__((ext_vector_type(8))) short short8;
typedef __attribute__((ext_vector_type(4))) float f32x4;
typedef __attribute__((ext_vector_type(4))) unsigned int u32x4;

static __device__ __forceinline__ unsigned short f2bf(float f) {
  unsigned u = __float_as_uint(f);
  u += 0x7fff + ((u >> 16) & 1);
  return (unsigned short)(u >> 16);
}
static __device__ __forceinline__ float bf2f(unsigned short b) {
  return __uint_as_float(((unsigned)b) << 16);
}

#if __has_builtin(__builtin_amdgcn_exp2f)
#define EXP2F(x) __builtin_amdgcn_exp2f(x)
#else
#define EXP2F(x) exp2f(x)
#endif
#if __has_builtin(__builtin_amdgcn_rcpf)
#define RCPF(x) __builtin_amdgcn_rcpf(x)
#else
#define RCPF(x) (1.0f / (x))
#endif

static __device__ __forceinline__ float sigm(float x) {
  return RCPF(1.0f + EXP2F(-1.4426950408889634f * x));
}
static __device__ __forceinline__ float tanh_(float x) {
  return 2.0f * RCPF(1.0f + EXP2F(-2.8853900817779268f * x)) - 1.0f;
}

// LDS ushort index: row r (0..31), 8-ushort block cb (0..7), swizzled.
static __device__ __forceinline__ int hidx(int r, int cb) {
  return r * 64 + ((cb ^ (r & 7)) << 3);
}

__global__ void k_zero(float* social) {
  social[threadIdx.x] = 0.0f;  // 1024 threads == 16*64 floats
}

#define MFMA_BF16 __builtin_amdgcn_mfma_f32_16x16x32_bf16

// ROUND-4 PROVEN INNER LOOP, duplicated for a SECOND independent neighbor
// group per wave (ILP play).  Round-4 analysis: kernel is latency-bound at
// 2 waves/SIMD (reg granule: ~96 arch + 64 acc W-frags -> 256 granule), VALU
// fill only 55%.  Two independent MFMA->activation chains per wave double the
// independent work per SIMD without touching the proven dataflow; barriers
// per neighbor halve.  W (Bhi/Blo) and BX fragments are SHARED by both
// groups; only acc/c/A-frags duplicate (+~32 arch regs, well under the 256
// budget — r1/r2's extra 8.9MB writes occurred at BOTH NPB=16 and 32 in the
// transposed structure, so they were structural, not reg-count).
// launch_bounds(256, 2): min 2 waves/EU -> 256-VGPR budget. (256,4) pins
// arch-VGPRs to 64 and spills the 64-reg W-fragment set (earlier rounds).
__global__ __launch_bounds__(256, 2)
void k_neigh(
    const float* __restrict__ tgt,   // 15*1*2
    const float* __restrict__ oth,   // 15*N*2
    const int* __restrict__ mask,    // 15*N
    const float* __restrict__ W_ih,  // 256*2
    const float* __restrict__ b_ih,  // 256
    const float* __restrict__ W_hh,  // 256*64
    const float* __restrict__ b_hh,  // 256
    float* __restrict__ social,      // 16*64, pre-zeroed
    float* __restrict__ ht_out)      // 64 (target-LSTM final h)
{
  __shared__ __align__(16) unsigned short h2[2][NPB][HDIM];  // h as bf16
  // per (t,n): 8 ushorts {x0hi,x0hi,x0lo,x1hi,x1hi,x1lo,1,1} + 16B zero slot
  __shared__ __align__(16) unsigned short xbf[ZOFF + 8];
  __shared__ float xs14[NPB][2];
  __shared__ float tht[HDIM];
  __shared__ float tgb[256];

  const int tid = threadIdx.x;

  if (blockIdx.x == 0) {
    // ---- target LSTM, fp32 exact; dispatched FIRST so it hides under the
    // neighbor grid.  Block-uniform branch; all threads hit barriers.
    const float bias = b_ih[tid] + b_hh[tid];
    const float wi0 = W_ih[tid * 2], wi1 = W_ih[tid * 2 + 1];
    const float4* Wr = (const float4*)&W_hh[tid * 64];
    if (tid < HDIM) tht[tid] = 0.0f;
    float ct = 0.0f;
    __syncthreads();
    for (int t = 0; t < OBS; ++t) {
      const float x0 = tgt[t * 2], x1 = tgt[t * 2 + 1];
      float acc = bias + x0 * wi0 + x1 * wi1;
#pragma unroll 4
      for (int k4 = 0; k4 < 16; ++k4) {
        const float4 wv = Wr[k4];
        const float4 hv = *(const float4*)&tht[k4 * 4];
        acc += wv.x * hv.x + wv.y * hv.y + wv.z * hv.z + wv.w * hv.w;
      }
      tgb[tid] = acc;
      __syncthreads();
      if (tid < HDIM) {
        const float cn =
            sigm(tgb[64 + tid]) * ct + sigm(tgb[tid]) * tanh_(tgb[128 + tid]);
        ct = cn;
        tht[tid] = sigm(tgb[192 + tid]) * tanh_(cn);
      }
      __syncthreads();
    }
    if (tid < HDIM) ht_out[tid] = tht[tid];
    return;
  }

  const int l = tid & 63;
  const int w = tid >> 6;   // wave id 0..3 -> owns gate-col slice w*16..w*16+15
  const int t15 = l & 15;
  const int g4 = l >> 4;
  const int n0 = (blockIdx.x - 1) * NPB;

  // ---- stage x hi/lo MFMA table + last-step raw positions (480 items) ----
  for (int i = tid; i < OBS * NPB; i += 256) {
    const int t = i >> 5, n = i & 31;
    const int gn = n0 + n;
    float x0 = 0.0f, x1 = 0.0f;
    if (gn < NTOT) {
      const float2 xv = *(const float2*)&oth[(t * NTOT + gn) * 2];
      x0 = xv.x; x1 = xv.y;
    }
    const unsigned short xh0 = f2bf(x0);
    const unsigned short xl0 = f2bf(x0 - bf2f(xh0));
    const unsigned short xh1 = f2bf(x1);
    const unsigned short xl1 = f2bf(x1 - bf2f(xh1));
    u32x4 d;
    d.x = (unsigned)xh0 | ((unsigned)xh0 << 16);  // k0=x0hi k1=x0hi
    d.y = (unsigned)xl0 | ((unsigned)xh1 << 16);  // k2=x0lo k3=x1hi
    d.z = (unsigned)xh1 | ((unsigned)xl1 << 16);  // k4=x1hi k5=x1lo
    d.w = 0x3F803F80u;                            // k6=1    k7=1
    *(u32x4*)&xbf[i * 8] = d;
    if (t == OBS - 1) { xs14[n][0] = x0; xs14[n][1] = x1; }
  }
  if (tid == 255) {
    u32x4 zz = {0u, 0u, 0u, 0u};
    *(u32x4*)&xbf[ZOFF] = zz;
  }
  // zero h buffer 0 (32 rows x 64 ushorts = 1024 uints)
  for (int i = tid; i < NPB * HDIM / 2; i += 256) ((unsigned int*)h2[0])[i] = 0u;

  // persistent W fragments: W_hh^T slices for this wave's gate cols,
  // RNE hi/lo split (proven indexing; shared by both neighbor groups)
  short8 Bhi0, Bhi1, Bhi2, Bhi3, Bhi4, Bhi5, Bhi6, Bhi7;
  short8 Blo0, Blo1, Blo2, Blo3, Blo4, Blo5, Blo6, Blo7;
#define LOADB(q, kt, BH, BL)                                        \
  {                                                                 \
    const float* wp = &W_hh[(q * 64 + w * 16 + t15) * 64 + kt * 32 + g4 * 8]; \
    _Pragma("unroll") for (int j = 0; j < 8; ++j) {                 \
      float wv = wp[j];                                             \
      unsigned short hi = f2bf(wv);                                 \
      unsigned short lo = f2bf(wv - bf2f(hi));                      \
      BH[j] = (short)hi;                                            \
      BL[j] = (short)lo;                                            \
    }                                                               \
  }
  LOADB(0, 0, Bhi0, Blo0) LOADB(0, 1, Bhi1, Blo1)
  LOADB(1, 0, Bhi2, Blo2) LOADB(1, 1, Bhi3, Blo3)
  LOADB(2, 0, Bhi4, Blo4) LOADB(2, 1, Bhi5, Blo5)
  LOADB(3, 0, Bhi6, Blo6) LOADB(3, 1, Bhi7, Blo7)
#undef LOADB

  // ---- B_x fragments: W_ih + bias as MFMA B-operand (shared by groups).
  // k-slots pair with xbf rows: dot vs {x0hi,x0hi,x0lo,x1hi,x1hi,x1lo,1,1}
  // = w0*x0 + w1*x1 + bias (hi*hi+hi*lo+lo*hi each) — proven in r1/r2/r4.
  short8 BX0, BX1, BX2, BX3;
  {
    u32x4 z4 = {0u, 0u, 0u, 0u};
    BX0 = BX1 = BX2 = BX3 = __builtin_bit_cast(short8, z4);
    if (g4 == 0) {
#pragma unroll
      for (int q = 0; q < 4; ++q) {
        const int G = q * 64 + w * 16 + t15;
        const float w0 = W_ih[G * 2 + 0], w1 = W_ih[G * 2 + 1];
        const float bs = b_ih[G] + b_hh[G];
        const unsigned short w0h = f2bf(w0), w0l = f2bf(w0 - bf2f(w0h));
        const unsigned short w1h = f2bf(w1), w1l = f2bf(w1 - bf2f(w1h));
        const unsigned short bh = f2bf(bs), bl = f2bf(bs - bf2f(bh));
        u32x4 d;
        d.x = (unsigned)w0h | ((unsigned)w0l << 16);
        d.y = (unsigned)w0h | ((unsigned)w1h << 16);
        d.z = (unsigned)w1l | ((unsigned)w1h << 16);
        d.w = (unsigned)bh | ((unsigned)bl << 16);
        const short8 v = __builtin_bit_cast(short8, d);
        if (q == 0) BX0 = v;
        else if (q == 1) BX1 = v;
        else if (q == 2) BX2 = v;
        else BX3 = v;
      }
    }
  }

  // A_x read offsets: g4==0 lanes walk the table; others broadcast zero slot.
  int xo = (g4 == 0) ? (t15 * 8) : ZOFF;
  const int xst = (g4 == 0) ? (NPB * 8) : 0;
  const int xg1 = (g4 == 0) ? (16 * 8) : 0;  // group-1 delta within a t-row

  f32x4 c0 = (f32x4){0.f, 0.f, 0.f, 0.f};
  f32x4 c1 = (f32x4){0.f, 0.f, 0.f, 0.f};
  const float refx = tgt[14 * 2 + 0];
  const float refy = tgt[14 * 2 + 1];

  __syncthreads();

  for (int t = 0; t < OBS; ++t) {
    const int cur = t & 1, nxt = cur ^ 1;
    const unsigned short* hb = &h2[cur][0][0];
    // A fragments: group 0 = rows 0..15, group 1 = rows 16..31
    const short8 Ax0 = *(const short8*)&xbf[xo];
    const short8 Ax1 = *(const short8*)&xbf[xo + xg1];
    const short8 A00 = *(const short8*)&hb[hidx(t15, g4)];
    const short8 A01 = *(const short8*)&hb[hidx(t15, 4 + g4)];
    const short8 A10 = *(const short8*)&hb[hidx(16 + t15, g4)];
    const short8 A11 = *(const short8*)&hb[hidx(16 + t15, 4 + g4)];
    xo += xst;

    const f32x4 z = (f32x4){0.f, 0.f, 0.f, 0.f};
    // group 0
    f32x4 p0 = MFMA_BF16(Ax0, BX0, z, 0, 0, 0);
    f32x4 p1 = MFMA_BF16(Ax0, BX1, z, 0, 0, 0);
    f32x4 p2 = MFMA_BF16(Ax0, BX2, z, 0, 0, 0);
    f32x4 p3 = MFMA_BF16(Ax0, BX3, z, 0, 0, 0);
    // group 1 (independent chain, interleaved by the scheduler)
    f32x4 q0 = MFMA_BF16(Ax1, BX0, z, 0, 0, 0);
    f32x4 q1 = MFMA_BF16(Ax1, BX1, z, 0, 0, 0);
    f32x4 q2 = MFMA_BF16(Ax1, BX2, z, 0, 0, 0);
    f32x4 q3 = MFMA_BF16(Ax1, BX3, z, 0, 0, 0);
    p0 = MFMA_BF16(A00, Bhi0, p0, 0, 0, 0);
    p1 = MFMA_BF16(A00, Bhi2, p1, 0, 0, 0);
    p2 = MFMA_BF16(A00, Bhi4, p2, 0, 0, 0);
    p3 = MFMA_BF16(A00, Bhi6, p3, 0, 0, 0);
    q0 = MFMA_BF16(A10, Bhi0, q0, 0, 0, 0);
    q1 = MFMA_BF16(A10, Bhi2, q1, 0, 0, 0);
    q2 = MFMA_BF16(A10, Bhi4, q2, 0, 0, 0);
    q3 = MFMA_BF16(A10, Bhi6, q3, 0, 0, 0);
    p0 = MFMA_BF16(A01, Bhi1, p0, 0, 0, 0);
    p1 = MFMA_BF16(A01, Bhi3, p1, 0, 0, 0);
    p2 = MFMA_BF16(A01, Bhi5, p2, 0, 0, 0);
    p3 = MFMA_BF16(A01, Bhi7, p3, 0, 0, 0);
    q0 = MFMA_BF16(A11, Bhi1, q0, 0, 0, 0);
    q1 = MFMA_BF16(A11, Bhi3, q1, 0, 0, 0);
    q2 = MFMA_BF16(A11, Bhi5, q2, 0, 0, 0);
    q3 = MFMA_BF16(A11, Bhi7, q3, 0, 0, 0);
    p0 = MFMA_BF16(A00, Blo0, p0, 0, 0, 0);
    p1 = MFMA_BF16(A00, Blo2, p1, 0, 0, 0);
    p2 = MFMA_BF16(A00, Blo4, p2, 0, 0, 0);
    p3 = MFMA_BF16(A00, Blo6, p3, 0, 0, 0);
    q0 = MFMA_BF16(A10, Blo0, q0, 0, 0, 0);
    q1 = MFMA_BF16(A10, Blo2, q1, 0, 0, 0);
    q2 = MFMA_BF16(A10, Blo4, q2, 0, 0, 0);
    q3 = MFMA_BF16(A10, Blo6, q3, 0, 0, 0);
    p0 = MFMA_BF16(A01, Blo1, p0, 0, 0, 0);
    p1 = MFMA_BF16(A01, Blo3, p1, 0, 0, 0);
    p2 = MFMA_BF16(A01, Blo5, p2, 0, 0, 0);
    p3 = MFMA_BF16(A01, Blo7, p3, 0, 0, 0);
    q0 = MFMA_BF16(A11, Blo1, q0, 0, 0, 0);
    q1 = MFMA_BF16(A11, Blo3, q1, 0, 0, 0);
    q2 = MFMA_BF16(A11, Blo5, q2, 0, 0, 0);
    q3 = MFMA_BF16(A11, Blo7, q3, 0, 0, 0);

    if (t < OBS - 1) {
      unsigned short* hn = &h2[nxt][0][0];
      const int col = w * 16 + t15;
#pragma unroll
      for (int r = 0; r < 4; ++r) {
        // group 0
        {
          const float si = sigm(p0[r]), sf = sigm(p1[r]);
          const float tg = tanh_(p2[r]), so = sigm(p3[r]);
          const float cn = sf * c0[r] + si * tg;
          c0[r] = cn;
          hn[hidx(g4 * 4 + r, col >> 3) + (col & 7)] = f2bf(so * tanh_(cn));
        }
        // group 1
        {
          const float si = sigm(q0[r]), sf = sigm(q1[r]);
          const float tg = tanh_(q2[r]), so = sigm(q3[r]);
          const float cn = sf * c1[r] + si * tg;
          c1[r] = cn;
          hn[hidx(16 + g4 * 4 + r, col >> 3) + (col & 7)] =
              f2bf(so * tanh_(cn));
        }
      }
      __syncthreads();
    } else {
      // final step: compute h (fp32) and pool directly
#define POOL(P0, P1, P2, P3, C, G)                                         \
  {                                                                        \
    _Pragma("unroll") for (int r = 0; r < 4; ++r) {                        \
      const float si = sigm(P0[r]), sf = sigm(P1[r]);                      \
      const float tg = tanh_(P2[r]), so = sigm(P3[r]);                     \
      const float cn = sf * C[r] + si * tg;                                \
      const float h = so * tanh_(cn);                                      \
      const int nl = G * 16 + g4 * 4 + r;                                  \
      const int gn = n0 + nl;                                              \
      const float rx = xs14[nl][0] - refx;                                 \
      const float ry = xs14[nl][1] - refy;                                 \
      bool ok = (fabsf(rx) <= 2.0f) && (fabsf(ry) <= 2.0f) && (gn < NTOT); \
      const int cx = (int)truncf(rx) + 2; /* cw == 1.0 */                  \
      const int cy = (int)truncf(ry) + 2;                                  \
      ok = ok && (cx >= 0) && (cx < 4) && (cy >= 0) && (cy < 4);           \
      if (ok && mask[(OBS - 1) * NTOT + gn] != 0)                          \
        atomicAdd(&social[(cy * 4 + cx) * HDIM + w * 16 + t15], h);        \
    }                                                                      \
  }
      POOL(p0, p1, p2, p3, c0, 0)
      POOL(q0, q1, q2, q3, c1, 1)
#undef POOL
    }
  }
}

// Slim k_final (verified rounds 1-4): social MLP + readout only.
__global__ __launch_bounds__(512) void k_final(
    const float* __restrict__ W1, const float* __restrict__ b1,
    const float* __restrict__ W2, const float* __restrict__ b2,
    const float* __restrict__ Wc, const float* __restrict__ bc,
    const float* __restrict__ social, const float* __restrict__ ht_g,
    float* __restrict__ out)
{
  __shared__ float sv[1024];
  __shared__ float hid[64];
  __shared__ float comb[64];
  __shared__ float ht[64];

  const int tid = threadIdx.x;
  for (int i = tid; i < 1024; i += 512) sv[i] = social[i];
  if (tid < 64) ht[tid] = ht_g[tid];
  __syncthreads();

  const int wv = tid >> 6, ln = tid & 63;
  for (int o = wv; o < 64; o += 8) {
    float p = 0.0f;
#pragma unroll
    for (int it = 0; it < 16; ++it) {
      const int j = it * 64 + ln;
      p += sv[j] * W1[o * 1024 + j];
    }
#pragma unroll
    for (int off = 32; off > 0; off >>= 1) p += __shfl_down(p, off);
    if (ln == 0) hid[o] = fmaxf(p + b1[o], 0.0f);
  }
  __syncthreads();
  for (int o = wv; o < 64; o += 8) {
    float p = hid[ln] * W2[o * 64 + ln];
#pragma unroll
    for (int off = 32; off > 0; off >>= 1) p += __shfl_down(p, off);
    if (ln == 0) comb[o] = ht[o] + p + b2[o];
  }
  __syncthreads();
  if (wv < 2) {
    float p = comb[ln] * Wc[wv * 64 + ln];
#pragma unroll
    for (int off = 32; off > 0; off >>= 1) p += __shfl_down(p, off);
    if (ln == 0) out[wv] = p + bc[wv];
  }
}

extern "C" void kernel_launch(void* const* d_in, const int* in_sizes, int n_in,
                              void* d_out, int out_size, void* d_ws, size_t ws_size,
                              hipStream_t stream) {
  const float* tgt = (const float*)d_in[0];
  const float* oth = (const float*)d_in[1];
  const int* mask = (const int*)d_in[2];
  const float* W_ih = (const float*)d_in[3];
  const float* b_ih = (const float*)d_in[4];
  const float* W_hh = (const float*)d_in[5];
  const float* b_hh = (const float*)d_in[6];
  const float* W1 = (const float*)d_in[7];
  const float* b1 = (const float*)d_in[8];
  const float* W2 = (const float*)d_in[9];
  const float* b2 = (const float*)d_in[10];
  const float* Wc = (const float*)d_in[11];
  const float* bc = (const float*)d_in[12];
  float* social = (float*)d_ws;          // ws[0..1023]
  float* ht = social + 1024;             // ws[1024..1087] (target-LSTM h)
  float* out = (float*)d_out;

  hipLaunchKernelGGL(k_zero, dim3(1), dim3(1024), 0, stream, social);
  hipLaunchKernelGGL(k_neigh, dim3(NBLK_N + 1), dim3(256), 0, stream,
                     tgt, oth, mask, W_ih, b_ih, W_hh, b_hh, social, ht);
  hipLaunchKernelGGL(k_final, dim3(1), dim3(512), 0, stream,
                     W1, b1, W2, b2, Wc, bc, social, ht, out);
}

// Round 6
// 120.493 us; speedup vs baseline: 1.1063x; 1.1063x over previous
//
#include <hip/hip_runtime.h>
#include <stdint.h>

#define OBS 15
#define NTOT 50000
#define HDIM 64
#define NPB 16               // neighbors per block (50000 = 3125 * 16, exact)
#define NBLK_N 3125          // neighbor blocks; blockIdx 0 runs the target LSTM
#define ZOFF (OBS * NPB * 8) // ushort index of the 16B zero slot in xbf

typedef __attribute__((ext_vector_type(8))) short short8;
typedef __attribute__((ext_vector_type(4))) float f32x4;
typedef __attribute__((ext_vector_type(4))) unsigned int u32x4;

#define KLOG2E 1.4426950408889634f   // log2(e)
#define KLOG2E2 2.8853900817779268f  // 2*log2(e)

static __device__ __forceinline__ unsigned short f2bf(float f) {
  unsigned u = __float_as_uint(f);
  u += 0x7fff + ((u >> 16) & 1);
  return (unsigned short)(u >> 16);
}
static __device__ __forceinline__ float bf2f(unsigned short b) {
  return __uint_as_float(((unsigned)b) << 16);
}

#if __has_builtin(__builtin_amdgcn_exp2f)
#define EXP2F(x) __builtin_amdgcn_exp2f(x)
#else
#define EXP2F(x) exp2f(x)
#endif
#if __has_builtin(__builtin_amdgcn_rcpf)
#define RCPF(x) __builtin_amdgcn_rcpf(x)
#else
#define RCPF(x) (1.0f / (x))
#endif

static __device__ __forceinline__ float sigm(float x) {
  return RCPF(1.0f + EXP2F(-KLOG2E * x));
}
static __device__ __forceinline__ float tanh_(float x) {
  return 2.0f * RCPF(1.0f + EXP2F(-KLOG2E2 * x)) - 1.0f;
}

// LDS ushort index: row r (0..15), 8-ushort block cb (0..7), swizzled.
static __device__ __forceinline__ int hidx(int r, int cb) {
  return r * 64 + ((cb ^ (r & 7)) << 3);
}

__global__ void k_zero(float* social) {
  social[threadIdx.x] = 0.0f;  // 1024 threads == 16*64 floats
}

#define MFMA_BF16 __builtin_amdgcn_mfma_f32_16x16x32_bf16

// ROUND-4 PROVEN STRUCTURE (126.1 us) restored exactly; round 5's 2-group ILP
// variant regressed (cross-block TLP, not intra-wave ILP, fills this kernel's
// idle issue slots — NPB=16 / 3126 blocks is the right shape).
// NEW in round 6 (activation-issue cut; ~900 -> ~700 VALU cyc per wave-step):
//  (1) exp2 scale constants folded into W/bias at fragment load
//      (i,f,o rows x -log2(e); g rows x -2log2(e)) — kills 4 muls/neighbor-r.
//  (2) fused-rcp activations: sig(i)*tanh(g) and sig(o)*tanh(cn) each share
//      ONE rcp of a product -> 8 trans (5 exp + 3 rcp) instead of 10 per
//      neighbor-r.  Gates bounded (~|9|) so exp2 args <= ~26: no inf/NaN.
// launch_bounds(256, 2): min 2 waves/EU -> 256-VGPR budget. (256,4) pins
// arch-VGPRs to 64 and spills the 64-reg W-fragment set (earlier rounds).
__global__ __launch_bounds__(256, 2)
void k_neigh(
    const float* __restrict__ tgt,   // 15*1*2
    const float* __restrict__ oth,   // 15*N*2
    const int* __restrict__ mask,    // 15*N
    const float* __restrict__ W_ih,  // 256*2
    const float* __restrict__ b_ih,  // 256
    const float* __restrict__ W_hh,  // 256*64
    const float* __restrict__ b_hh,  // 256
    float* __restrict__ social,      // 16*64, pre-zeroed
    float* __restrict__ ht_out)      // 64 (target-LSTM final h)
{
  __shared__ __align__(16) unsigned short h2[2][NPB][HDIM];  // h as bf16
  // per (t,n): 8 ushorts {x0hi,x0hi,x0lo,x1hi,x1hi,x1lo,1,1} + 16B zero slot
  __shared__ __align__(16) unsigned short xbf[ZOFF + 8];
  __shared__ float xs14[NPB][2];
  __shared__ float tht[HDIM];
  __shared__ float tgb[256];

  const int tid = threadIdx.x;

  if (blockIdx.x == 0) {
    // ---- target LSTM, fp32 exact (raw unscaled weights); dispatched FIRST
    // so it hides under the neighbor grid.  Block-uniform branch.
    const float bias = b_ih[tid] + b_hh[tid];
    const float wi0 = W_ih[tid * 2], wi1 = W_ih[tid * 2 + 1];
    const float4* Wr = (const float4*)&W_hh[tid * 64];
    if (tid < HDIM) tht[tid] = 0.0f;
    float ct = 0.0f;
    __syncthreads();
    for (int t = 0; t < OBS; ++t) {
      const float x0 = tgt[t * 2], x1 = tgt[t * 2 + 1];
      float acc = bias + x0 * wi0 + x1 * wi1;
#pragma unroll 4
      for (int k4 = 0; k4 < 16; ++k4) {
        const float4 wv = Wr[k4];
        const float4 hv = *(const float4*)&tht[k4 * 4];
        acc += wv.x * hv.x + wv.y * hv.y + wv.z * hv.z + wv.w * hv.w;
      }
      tgb[tid] = acc;
      __syncthreads();
      if (tid < HDIM) {
        const float cn =
            sigm(tgb[64 + tid]) * ct + sigm(tgb[tid]) * tanh_(tgb[128 + tid]);
        ct = cn;
        tht[tid] = sigm(tgb[192 + tid]) * tanh_(cn);
      }
      __syncthreads();
    }
    if (tid < HDIM) ht_out[tid] = tht[tid];
    return;
  }

  const int l = tid & 63;
  const int w = tid >> 6;   // wave id 0..3 -> owns gate-col slice w*16..w*16+15
  const int t15 = l & 15;
  const int g4 = l >> 4;
  const int n0 = (blockIdx.x - 1) * NPB;

  // ---- stage x hi/lo MFMA table + last-step raw positions (240 items) ----
  if (tid < OBS * NPB) {
    const int t = tid >> 4, n = tid & 15;
    const int gn = n0 + n;
    const float x0 = oth[(t * NTOT + gn) * 2 + 0];
    const float x1 = oth[(t * NTOT + gn) * 2 + 1];
    const unsigned short xh0 = f2bf(x0);
    const unsigned short xl0 = f2bf(x0 - bf2f(xh0));
    const unsigned short xh1 = f2bf(x1);
    const unsigned short xl1 = f2bf(x1 - bf2f(xh1));
    u32x4 d;
    d.x = (unsigned)xh0 | ((unsigned)xh0 << 16);  // k0=x0hi k1=x0hi
    d.y = (unsigned)xl0 | ((unsigned)xh1 << 16);  // k2=x0lo k3=x1hi
    d.z = (unsigned)xh1 | ((unsigned)xl1 << 16);  // k4=x1hi k5=x1lo
    d.w = 0x3F803F80u;                            // k6=1    k7=1
    *(u32x4*)&xbf[tid * 8] = d;
    if (t == OBS - 1) { xs14[n][0] = x0; xs14[n][1] = x1; }
  }
  if (tid == 255) {
    u32x4 zz = {0u, 0u, 0u, 0u};
    *(u32x4*)&xbf[ZOFF] = zz;
  }
  // zero h buffer 0
  for (int i = tid; i < NPB * HDIM / 2; i += 256) ((unsigned int*)h2[0])[i] = 0u;

  // persistent B fragments: W_hh^T slices for this wave's gate cols, PRE-
  // SCALED by the exp2 constant of the consuming activation, RNE hi/lo split.
  short8 Bhi0, Bhi1, Bhi2, Bhi3, Bhi4, Bhi5, Bhi6, Bhi7;
  short8 Blo0, Blo1, Blo2, Blo3, Blo4, Blo5, Blo6, Blo7;
#define LOADB(q, kt, BH, BL, SC)                                              \
  {                                                                           \
    const float* wp = &W_hh[(q * 64 + w * 16 + t15) * 64 + kt * 32 + g4 * 8]; \
    _Pragma("unroll") for (int j = 0; j < 8; ++j) {                           \
      float wv = wp[j] * (SC);                                                \
      unsigned short hi = f2bf(wv);                                           \
      unsigned short lo = f2bf(wv - bf2f(hi));                                \
      BH[j] = (short)hi;                                                      \
      BL[j] = (short)lo;                                                      \
    }                                                                         \
  }
  LOADB(0, 0, Bhi0, Blo0, -KLOG2E)  LOADB(0, 1, Bhi1, Blo1, -KLOG2E)
  LOADB(1, 0, Bhi2, Blo2, -KLOG2E)  LOADB(1, 1, Bhi3, Blo3, -KLOG2E)
  LOADB(2, 0, Bhi4, Blo4, -KLOG2E2) LOADB(2, 1, Bhi5, Blo5, -KLOG2E2)
  LOADB(3, 0, Bhi6, Blo6, -KLOG2E)  LOADB(3, 1, Bhi7, Blo7, -KLOG2E)
#undef LOADB

  // ---- B_x fragments: W_ih + bias as MFMA B-operand, same pre-scaling.
  // k-slots pair with xbf rows: dot vs {x0hi,x0hi,x0lo,x1hi,x1hi,x1lo,1,1}
  // = sc*(w0*x0 + w1*x1 + bias) (hi*hi+hi*lo+lo*hi each) — proven pairing.
  short8 BX0, BX1, BX2, BX3;
  {
    u32x4 z4 = {0u, 0u, 0u, 0u};
    BX0 = BX1 = BX2 = BX3 = __builtin_bit_cast(short8, z4);
    if (g4 == 0) {
#pragma unroll
      for (int q = 0; q < 4; ++q) {
        const float sc = (q == 2) ? -KLOG2E2 : -KLOG2E;
        const int G = q * 64 + w * 16 + t15;
        const float w0 = W_ih[G * 2 + 0] * sc, w1 = W_ih[G * 2 + 1] * sc;
        const float bs = (b_ih[G] + b_hh[G]) * sc;
        const unsigned short w0h = f2bf(w0), w0l = f2bf(w0 - bf2f(w0h));
        const unsigned short w1h = f2bf(w1), w1l = f2bf(w1 - bf2f(w1h));
        const unsigned short bh = f2bf(bs), bl = f2bf(bs - bf2f(bh));
        u32x4 d;
        d.x = (unsigned)w0h | ((unsigned)w0l << 16);
        d.y = (unsigned)w0h | ((unsigned)w1h << 16);
        d.z = (unsigned)w1l | ((unsigned)w1h << 16);
        d.w = (unsigned)bh | ((unsigned)bl << 16);
        const short8 v = __builtin_bit_cast(short8, d);
        if (q == 0) BX0 = v;
        else if (q == 1) BX1 = v;
        else if (q == 2) BX2 = v;
        else BX3 = v;
      }
    }
  }

  // A_x read offset: g4==0 lanes walk the xbf table, others broadcast-read
  // the zero slot (uniform address -> no conflict).
  int xo = (g4 == 0) ? (t15 * 8) : ZOFF;
  const int xst = (g4 == 0) ? (NPB * 8) : 0;

  f32x4 c = (f32x4){0.f, 0.f, 0.f, 0.f};
  const float refx = tgt[14 * 2 + 0];
  const float refy = tgt[14 * 2 + 1];

  __syncthreads();

  for (int t = 0; t < OBS; ++t) {
    const int cur = t & 1, nxt = cur ^ 1;
    // A_x fragment first (chain head), then h A-fragments
    const short8 Ax = *(const short8*)&xbf[xo];
    short8 A0 = *(const short8*)&h2[cur][0][hidx(t15, g4)];
    short8 A1 = *(const short8*)&h2[cur][0][hidx(t15, 4 + g4)];
    xo += xst;

    // acc0 = -log2e*i, acc1 = -log2e*f, acc2 = -2log2e*g, acc3 = -log2e*o
    const f32x4 z = (f32x4){0.f, 0.f, 0.f, 0.f};
    f32x4 acc0 = MFMA_BF16(Ax, BX0, z, 0, 0, 0);
    f32x4 acc1 = MFMA_BF16(Ax, BX1, z, 0, 0, 0);
    f32x4 acc2 = MFMA_BF16(Ax, BX2, z, 0, 0, 0);
    f32x4 acc3 = MFMA_BF16(Ax, BX3, z, 0, 0, 0);
    acc0 = MFMA_BF16(A0, Bhi0, acc0, 0, 0, 0);
    acc1 = MFMA_BF16(A0, Bhi2, acc1, 0, 0, 0);
    acc2 = MFMA_BF16(A0, Bhi4, acc2, 0, 0, 0);
    acc3 = MFMA_BF16(A0, Bhi6, acc3, 0, 0, 0);
    acc0 = MFMA_BF16(A1, Bhi1, acc0, 0, 0, 0);
    acc1 = MFMA_BF16(A1, Bhi3, acc1, 0, 0, 0);
    acc2 = MFMA_BF16(A1, Bhi5, acc2, 0, 0, 0);
    acc3 = MFMA_BF16(A1, Bhi7, acc3, 0, 0, 0);
    acc0 = MFMA_BF16(A0, Blo0, acc0, 0, 0, 0);
    acc1 = MFMA_BF16(A0, Blo2, acc1, 0, 0, 0);
    acc2 = MFMA_BF16(A0, Blo4, acc2, 0, 0, 0);
    acc3 = MFMA_BF16(A0, Blo6, acc3, 0, 0, 0);
    acc0 = MFMA_BF16(A1, Blo1, acc0, 0, 0, 0);
    acc1 = MFMA_BF16(A1, Blo3, acc1, 0, 0, 0);
    acc2 = MFMA_BF16(A1, Blo5, acc2, 0, 0, 0);
    acc3 = MFMA_BF16(A1, Blo7, acc3, 0, 0, 0);

    // fused-rcp LSTM cell: ei..eo are exp2 of pre-scaled gates.
    //   sig(f)          = 1/(1+ef)
    //   sig(i)*tanh(g)  = (1-eg)/((1+ei)(1+eg))
    //   sig(o)*tanh(cn) = (1-ecn)/((1+eo)(1+ecn))
    if (t < OBS - 1) {
#pragma unroll
      for (int r = 0; r < 4; ++r) {
        const float ei = EXP2F(acc0[r]);
        const float ef = EXP2F(acc1[r]);
        const float eg = EXP2F(acc2[r]);
        const float eo = EXP2F(acc3[r]);
        const float sf = RCPF(1.0f + ef);
        const float rig = RCPF((1.0f + ei) * (1.0f + eg));
        const float cn = c[r] * sf + (1.0f - eg) * rig;
        c[r] = cn;
        const float ecn = EXP2F(-KLOG2E2 * cn);
        const float ro = RCPF((1.0f + eo) * (1.0f + ecn));
        const float h = (1.0f - ecn) * ro;
        const int n = g4 * 4 + r;
        const int col = w * 16 + t15;
        h2[nxt][0][hidx(n, col >> 3) + (col & 7)] = f2bf(h);
      }
      __syncthreads();
    } else {
      // final step: compute h (fp32) and pool directly
#pragma unroll
      for (int r = 0; r < 4; ++r) {
        const float ei = EXP2F(acc0[r]);
        const float ef = EXP2F(acc1[r]);
        const float eg = EXP2F(acc2[r]);
        const float eo = EXP2F(acc3[r]);
        const float sf = RCPF(1.0f + ef);
        const float rig = RCPF((1.0f + ei) * (1.0f + eg));
        const float cn = c[r] * sf + (1.0f - eg) * rig;
        const float ecn = EXP2F(-KLOG2E2 * cn);
        const float ro = RCPF((1.0f + eo) * (1.0f + ecn));
        const float h = (1.0f - ecn) * ro;
        const int nl = g4 * 4 + r;
        const int gn = n0 + nl;
        const float rx = xs14[nl][0] - refx;
        const float ry = xs14[nl][1] - refy;
        bool ok = (fabsf(rx) <= 2.0f) && (fabsf(ry) <= 2.0f);
        const int cx = (int)truncf(rx) + 2;  // cw == 1.0
        const int cy = (int)truncf(ry) + 2;
        ok = ok && (cx >= 0) && (cx < 4) && (cy >= 0) && (cy < 4);
        if (ok && mask[(OBS - 1) * NTOT + gn] != 0)
          atomicAdd(&social[(cy * 4 + cx) * HDIM + w * 16 + t15], h);
      }
    }
  }
}

// Slim k_final (verified rounds 1-5): social MLP + readout only.
__global__ __launch_bounds__(512) void k_final(
    const float* __restrict__ W1, const float* __restrict__ b1,
    const float* __restrict__ W2, const float* __restrict__ b2,
    const float* __restrict__ Wc, const float* __restrict__ bc,
    const float* __restrict__ social, const float* __restrict__ ht_g,
    float* __restrict__ out)
{
  __shared__ float sv[1024];
  __shared__ float hid[64];
  __shared__ float comb[64];
  __shared__ float ht[64];

  const int tid = threadIdx.x;
  for (int i = tid; i < 1024; i += 512) sv[i] = social[i];
  if (tid < 64) ht[tid] = ht_g[tid];
  __syncthreads();

  const int wv = tid >> 6, ln = tid & 63;
  for (int o = wv; o < 64; o += 8) {
    float p = 0.0f;
#pragma unroll
    for (int it = 0; it < 16; ++it) {
      const int j = it * 64 + ln;
      p += sv[j] * W1[o * 1024 + j];
    }
#pragma unroll
    for (int off = 32; off > 0; off >>= 1) p += __shfl_down(p, off);
    if (ln == 0) hid[o] = fmaxf(p + b1[o], 0.0f);
  }
  __syncthreads();
  for (int o = wv; o < 64; o += 8) {
    float p = hid[ln] * W2[o * 64 + ln];
#pragma unroll
    for (int off = 32; off > 0; off >>= 1) p += __shfl_down(p, off);
    if (ln == 0) comb[o] = ht[o] + p + b2[o];
  }
  __syncthreads();
  if (wv < 2) {
    float p = comb[ln] * Wc[wv * 64 + ln];
#pragma unroll
    for (int off = 32; off > 0; off >>= 1) p += __shfl_down(p, off);
    if (ln == 0) out[wv] = p + bc[wv];
  }
}

extern "C" void kernel_launch(void* const* d_in, const int* in_sizes, int n_in,
                              void* d_out, int out_size, void* d_ws, size_t ws_size,
                              hipStream_t stream) {
  const float* tgt = (const float*)d_in[0];
  const float* oth = (const float*)d_in[1];
  const int* mask = (const int*)d_in[2];
  const float* W_ih = (const float*)d_in[3];
  const float* b_ih = (const float*)d_in[4];
  const float* W_hh = (const float*)d_in[5];
  const float* b_hh = (const float*)d_in[6];
  const float* W1 = (const float*)d_in[7];
  const float* b1 = (const float*)d_in[8];
  const float* W2 = (const float*)d_in[9];
  const float* b2 = (const float*)d_in[10];
  const float* Wc = (const float*)d_in[11];
  const float* bc = (const float*)d_in[12];
  float* social = (float*)d_ws;          // ws[0..1023]
  float* ht = social + 1024;             // ws[1024..1087] (target-LSTM h)
  float* out = (float*)d_out;

  hipLaunchKernelGGL(k_zero, dim3(1), dim3(1024), 0, stream, social);
  hipLaunchKernelGGL(k_neigh, dim3(NBLK_N + 1), dim3(256), 0, stream,
                     tgt, oth, mask, W_ih, b_ih, W_hh, b_hh, social, ht);
  hipLaunchKernelGGL(k_final, dim3(1), dim3(512), 0, stream,
                     W1, b1, W2, b2, Wc, bc, social, ht, out);
}